// Round 1
// baseline (1029.710 us; speedup 1.0000x reference)
//
#include <hip/hip_runtime.h>

#define BB 16
#define CC 16
#define HH 384
#define WW 384
#define HWSZ (HH*WW)
#define CHW (CC*HWSZ)
#define KS 11

#define K2_WSTRIPS 3          // 3 * 128 = 384 columns
#define K2_HSEGS 4
#define K2_SEGH (HH/K2_HSEGS) // 96 rows per segment

// ---------------------------------------------------------------------------
// K1: per-(b,h) row — softmax over C, then 11-tap conv along W (center tap 0).
// Writes t = ConvW(softmax(x)).  No read amplification; p staged in LDS.
// ---------------------------------------------------------------------------
__global__ __launch_bounds__(WW) void k_softmax_convw(
    const float* __restrict__ xin, float* __restrict__ t,
    const float* __restrict__ spacings, const float* __restrict__ invtheta)
{
    const int h = blockIdx.x;
    const int b = blockIdx.y;
    const int w = threadIdx.x;
    __shared__ float p[CC][WW];

    const float* xb = xin + (size_t)b * CHW + (size_t)h * WW + w;
    float v[CC];
#pragma unroll
    for (int c = 0; c < CC; ++c) v[c] = xb[(size_t)c * HWSZ];

    float m = v[0];
#pragma unroll
    for (int c = 1; c < CC; ++c) m = fmaxf(m, v[c]);
    float s = 0.f;
#pragma unroll
    for (int c = 0; c < CC; ++c) { v[c] = __expf(v[c] - m); s += v[c]; }
    const float inv = 1.0f / s;
#pragma unroll
    for (int c = 0; c < CC; ++c) p[c][w] = v[c] * inv;

    // Per-sample W-axis taps (axis index 1): k[j] = exp(-0.5*(spacing*(j-5)*invtheta)^2), k[5]=0
    const float sc = spacings[b * 2 + 1] * invtheta[1];
    float kw[KS];
#pragma unroll
    for (int j = 0; j < KS; ++j) { float d = sc * (float)(j - 5); kw[j] = __expf(-0.5f * d * d); }
    kw[5] = 0.f;

    __syncthreads();

    float* tb = t + (size_t)b * CHW + (size_t)h * WW + w;
#pragma unroll
    for (int c = 0; c < CC; ++c) {
        float acc = 0.f;
#pragma unroll
        for (int j = 0; j < KS; ++j) {
            if (j == 5) continue;
            const int ww = w + j - 5;
            const float pv = (ww >= 0 && ww < WW) ? p[c][ww] : 0.f;
            acc = fmaf(kw[j], pv, acc);
        }
        tb[(size_t)c * HWSZ] = acc;
    }
}

// ---------------------------------------------------------------------------
// K2: per-(b,c,wstrip,hseg) — 11-tap conv along H via rolling register window,
// fused with x = x0 + sw * conv.  Writes x in place (reads only t and x0).
// ---------------------------------------------------------------------------
__global__ __launch_bounds__(128) void k_convh_add(
    const float* __restrict__ t, const float* __restrict__ x0,
    float* __restrict__ xout,
    const float* __restrict__ spacings, const float* __restrict__ invtheta,
    const float* __restrict__ swp)
{
    const int ws = blockIdx.x % K2_WSTRIPS;
    const int hs = blockIdx.x / K2_WSTRIPS;
    const int c  = blockIdx.y;
    const int b  = blockIdx.z;
    const int w  = ws * 128 + threadIdx.x;
    const int h0 = hs * K2_SEGH;

    const float sw = swp[0];
    const float sc = spacings[b * 2 + 0] * invtheta[0];  // H axis = spatial axis 0
    float kh[KS];
#pragma unroll
    for (int j = 0; j < KS; ++j) { float d = sc * (float)(j - 5); kh[j] = __expf(-0.5f * d * d); }
    kh[5] = 0.f;

    const size_t base = (size_t)(b * CC + c) * HWSZ + w;
    const float* tb = t   + base;
    const float* ub = x0  + base;
    float*       ob = xout + base;

    float win[KS];
#pragma unroll
    for (int j = 0; j < KS; ++j) {
        const int r = h0 + j - 5;
        win[j] = (r >= 0 && r < HH) ? tb[(size_t)r * WW] : 0.f;
    }

    for (int h = h0; h < h0 + K2_SEGH; ++h) {
        float acc = 0.f;
#pragma unroll
        for (int j = 0; j < KS; ++j) { if (j != 5) acc = fmaf(kh[j], win[j], acc); }
        ob[(size_t)h * WW] = ub[(size_t)h * WW] + sw * acc;
#pragma unroll
        for (int j = 0; j < KS - 1; ++j) win[j] = win[j + 1];
        const int nr = h + 6;
        win[KS - 1] = (nr < HH) ? tb[(size_t)nr * WW] : 0.f;
    }
}

// ---------------------------------------------------------------------------
// K3: in-place log_softmax over C per pixel (pointwise, safe in place).
// ---------------------------------------------------------------------------
__global__ __launch_bounds__(256) void k_logsoftmax(float* __restrict__ x)
{
    const int p = blockIdx.x * 256 + threadIdx.x;
    if (p >= BB * HWSZ) return;
    const int b = p / HWSZ;
    const int r = p - b * HWSZ;
    float* xb = x + (size_t)b * CHW + r;

    float v[CC];
#pragma unroll
    for (int c = 0; c < CC; ++c) v[c] = xb[(size_t)c * HWSZ];
    float m = v[0];
#pragma unroll
    for (int c = 1; c < CC; ++c) m = fmaxf(m, v[c]);
    float s = 0.f;
#pragma unroll
    for (int c = 0; c < CC; ++c) s += __expf(v[c] - m);
    const float l = m + __logf(s);
#pragma unroll
    for (int c = 0; c < CC; ++c) xb[(size_t)c * HWSZ] = v[c] - l;
}

// ---------------------------------------------------------------------------
extern "C" void kernel_launch(void* const* d_in, const int* in_sizes, int n_in,
                              void* d_out, int out_size, void* d_ws, size_t ws_size,
                              hipStream_t stream)
{
    const float* x0   = (const float*)d_in[0];  // (B,C,H,W) unaries
    const float* spac = (const float*)d_in[1];  // (B,2)
    const float* sw   = (const float*)d_in[2];  // scalar
    const float* it   = (const float*)d_in[3];  // (2,)

    float* xcur = (float*)d_out;  // evolving x (and final output)
    float* t    = (float*)d_ws;   // ConvW(softmax(x)) scratch, 151 MB

    dim3 g1(HH, BB);
    dim3 b1(WW);
    dim3 g2(K2_WSTRIPS * K2_HSEGS, CC, BB);
    dim3 b2(128);

    for (int n = 0; n < 5; ++n) {
        k_softmax_convw<<<g1, b1, 0, stream>>>(n == 0 ? x0 : xcur, t, spac, it);
        k_convh_add<<<g2, b2, 0, stream>>>(t, x0, xcur, spac, it, sw);
    }
    const int npix = BB * HWSZ;
    k_logsoftmax<<<(npix + 255) / 256, 256, 0, stream>>>(xcur);
}

// Round 2
// 762.733 us; speedup vs baseline: 1.3500x; 1.3500x over previous
//
#include <hip/hip_runtime.h>

#define BB 16
#define CC 16
#define HH 384
#define WW 384
#define WW4 (WW/4)
#define HWSZ (HH*WW)
#define HWSZ4 (HWSZ/4)
#define CHW (CC*HWSZ)
#define KS 11

#define K2_THREADS 256
#define K2_HSEGS 8
#define K2_SEGH (HH/K2_HSEGS) // 48 rows per segment
#define NCOL4 (CC*WW4)        // 1536 float4-columns per batch

// ---------------------------------------------------------------------------
// K1: per-(b,h) row — softmax over C, then 11-tap conv along W (center tap 0).
// Writes t = ConvW(softmax(x)).
// ---------------------------------------------------------------------------
__global__ __launch_bounds__(WW) void k_softmax_convw(
    const float* __restrict__ xin, float* __restrict__ t,
    const float* __restrict__ spacings, const float* __restrict__ invtheta)
{
    const int h = blockIdx.x;
    const int b = blockIdx.y;
    const int w = threadIdx.x;
    __shared__ float p[CC][WW];

    const float* xb = xin + (size_t)b * CHW + (size_t)h * WW + w;
    float v[CC];
#pragma unroll
    for (int c = 0; c < CC; ++c) v[c] = xb[(size_t)c * HWSZ];

    float m = v[0];
#pragma unroll
    for (int c = 1; c < CC; ++c) m = fmaxf(m, v[c]);
    float s = 0.f;
#pragma unroll
    for (int c = 0; c < CC; ++c) { v[c] = __expf(v[c] - m); s += v[c]; }
    const float inv = 1.0f / s;
#pragma unroll
    for (int c = 0; c < CC; ++c) p[c][w] = v[c] * inv;

    const float sc = spacings[b * 2 + 1] * invtheta[1];  // W axis = spatial axis 1
    float kw[KS];
#pragma unroll
    for (int j = 0; j < KS; ++j) { float d = sc * (float)(j - 5); kw[j] = __expf(-0.5f * d * d); }
    kw[5] = 0.f;

    __syncthreads();

    float* tb = t + (size_t)b * CHW + (size_t)h * WW + w;
#pragma unroll
    for (int c = 0; c < CC; ++c) {
        float acc = 0.f;
#pragma unroll
        for (int j = 0; j < KS; ++j) {
            if (j == 5) continue;
            const int ww = w + j - 5;
            const float pv = (ww >= 0 && ww < WW) ? p[c][ww] : 0.f;
            acc = fmaf(kw[j], pv, acc);
        }
        tb[(size_t)c * HWSZ] = acc;
    }
}

// ---------------------------------------------------------------------------
// K2: float4 column streaming — 11-tap conv along H with rolling float4
// window, fused with x = x0 + sw*conv. Thread owns 4 adjacent columns.
// Flattened (c, w4) column space -> coalesced 16B/lane loads.
// ---------------------------------------------------------------------------
__global__ __launch_bounds__(K2_THREADS) void k_convh_add(
    const float* __restrict__ t, const float* __restrict__ x0,
    float* __restrict__ xout,
    const float* __restrict__ spacings, const float* __restrict__ invtheta,
    const float* __restrict__ swp)
{
    const int colIdx = blockIdx.x * K2_THREADS + threadIdx.x;  // [0, 1536)
    const int c  = colIdx / WW4;
    const int w4 = colIdx - c * WW4;
    const int b  = blockIdx.z;
    const int h0 = blockIdx.y * K2_SEGH;

    const float sw = swp[0];
    const float sc = spacings[b * 2 + 0] * invtheta[0];  // H axis = spatial axis 0
    float kh[KS];
#pragma unroll
    for (int j = 0; j < KS; ++j) { float d = sc * (float)(j - 5); kh[j] = __expf(-0.5f * d * d); }
    kh[5] = 0.f;

    const size_t base4 = (size_t)(b * CC + c) * HWSZ4 + w4;
    const float4* tb = (const float4*)t  + base4;
    const float4* ub = (const float4*)x0 + base4;
    float4*       ob = (float4*)xout     + base4;

    const float4 z4 = make_float4(0.f, 0.f, 0.f, 0.f);
    float4 win[KS];
#pragma unroll
    for (int j = 0; j < KS; ++j) {
        const int r = h0 + j - 5;
        win[j] = (r >= 0 && r < HH) ? tb[(size_t)r * WW4] : z4;
    }

#pragma unroll 4
    for (int h = h0; h < h0 + K2_SEGH; ++h) {
        const int nr = h + 6;
        const float4 nt = (nr < HH) ? tb[(size_t)nr * WW4] : z4;  // prefetch next row
        const float4 u  = ub[(size_t)h * WW4];
        float ax = 0.f, ay = 0.f, az = 0.f, aw = 0.f;
#pragma unroll
        for (int j = 0; j < KS; ++j) {
            if (j == 5) continue;
            ax = fmaf(kh[j], win[j].x, ax);
            ay = fmaf(kh[j], win[j].y, ay);
            az = fmaf(kh[j], win[j].z, az);
            aw = fmaf(kh[j], win[j].w, aw);
        }
        float4 o;
        o.x = fmaf(sw, ax, u.x);
        o.y = fmaf(sw, ay, u.y);
        o.z = fmaf(sw, az, u.z);
        o.w = fmaf(sw, aw, u.w);
        ob[(size_t)h * WW4] = o;
#pragma unroll
        for (int j = 0; j < KS - 1; ++j) win[j] = win[j + 1];
        win[KS - 1] = nt;
    }
}

// ---------------------------------------------------------------------------
// K3: in-place log_softmax over C per pixel, float4-vectorized.
// ---------------------------------------------------------------------------
__global__ __launch_bounds__(256) void k_logsoftmax(float* __restrict__ x)
{
    const int p = blockIdx.x * 256 + threadIdx.x;
    if (p >= BB * HWSZ4) return;
    const int b = p / HWSZ4;
    const int r = p - b * HWSZ4;
    float4* xb = (float4*)x + (size_t)b * (CHW / 4) + r;

    float4 v[CC];
#pragma unroll
    for (int c = 0; c < CC; ++c) v[c] = xb[(size_t)c * HWSZ4];

    float4 m = v[0];
#pragma unroll
    for (int c = 1; c < CC; ++c) {
        m.x = fmaxf(m.x, v[c].x); m.y = fmaxf(m.y, v[c].y);
        m.z = fmaxf(m.z, v[c].z); m.w = fmaxf(m.w, v[c].w);
    }
    float4 s = make_float4(0.f, 0.f, 0.f, 0.f);
#pragma unroll
    for (int c = 0; c < CC; ++c) {
        s.x += __expf(v[c].x - m.x); s.y += __expf(v[c].y - m.y);
        s.z += __expf(v[c].z - m.z); s.w += __expf(v[c].w - m.w);
    }
    float4 l;
    l.x = m.x + __logf(s.x); l.y = m.y + __logf(s.y);
    l.z = m.z + __logf(s.z); l.w = m.w + __logf(s.w);
#pragma unroll
    for (int c = 0; c < CC; ++c) {
        float4 o;
        o.x = v[c].x - l.x; o.y = v[c].y - l.y;
        o.z = v[c].z - l.z; o.w = v[c].w - l.w;
        xb[(size_t)c * HWSZ4] = o;
    }
}

// ---------------------------------------------------------------------------
extern "C" void kernel_launch(void* const* d_in, const int* in_sizes, int n_in,
                              void* d_out, int out_size, void* d_ws, size_t ws_size,
                              hipStream_t stream)
{
    const float* x0   = (const float*)d_in[0];  // (B,C,H,W) unaries
    const float* spac = (const float*)d_in[1];  // (B,2)
    const float* sw   = (const float*)d_in[2];  // scalar
    const float* it   = (const float*)d_in[3];  // (2,)

    float* xcur = (float*)d_out;  // evolving x (and final output)
    float* t    = (float*)d_ws;   // ConvW(softmax(x)) scratch

    dim3 g1(HH, BB);
    dim3 b1(WW);
    dim3 g2(NCOL4 / K2_THREADS, K2_HSEGS, BB);  // (6, 8, 16)
    dim3 b2(K2_THREADS);

    for (int n = 0; n < 5; ++n) {
        k_softmax_convw<<<g1, b1, 0, stream>>>(n == 0 ? x0 : xcur, t, spac, it);
        k_convh_add<<<g2, b2, 0, stream>>>(t, x0, xcur, spac, it, sw);
    }
    const int npix4 = BB * HWSZ4;
    k_logsoftmax<<<(npix4 + 255) / 256, 256, 0, stream>>>(xcur);
}